// Round 12
// baseline (147.794 us; speedup 1.0000x reference)
//
#include <hip/hip_runtime.h>
#include <math.h>

#define N_ 4096
#define M_ 4096
#define D_ 8
#define TI 8                        // x-rows per block
#define TINY_F 1.17549435e-38f
#define LOG2E_F 1.44269504088896f
#define REPS 5                      // slope measurement: k = (bench - 86.6)/4

typedef float floatx2 __attribute__((ext_vector_type(2)));  // -> v_pk_*_f32

// Numerically stable softplus: log(1+exp(v)) = max(v,0) + log1p(exp(-|v|))
__device__ __forceinline__ float softplus_stable(float v) {
    return fmaxf(v, 0.0f) + log1pf(expf(-fabsf(v)));
}

__global__ __launch_bounds__(256) void rbf_kernel(
    const float* __restrict__ x,      // (N, D)
    const float* __restrict__ x2,     // (M, D)
    const float* __restrict__ ramp,   // (1,)
    const float* __restrict__ rls,    // (D,)
    float* __restrict__ out)          // (N, M)
{
    // [0..7] = (0.5/ls^2)*log2(e)  (exp folded into exp2), [8] = amp^2
    __shared__ float s_par[D_ + 1];
    if (threadIdx.x < D_) {
        float l = softplus_stable(rls[threadIdx.x]) + TINY_F;
        s_par[threadIdx.x] = (0.5f * LOG2E_F) / (l * l);
    } else if (threadIdx.x == D_) {
        float a = softplus_stable(ramp[0]) + TINY_F;
        s_par[D_] = a * a;
    }
    __syncthreads();

    // Dim-pair packed constants (one-time).
    floatx2 cp[4];
    cp[0] = floatx2{s_par[0], s_par[1]};
    cp[1] = floatx2{s_par[2], s_par[3]};
    cp[2] = floatx2{s_par[4], s_par[5]};
    cp[3] = floatx2{s_par[6], s_par[7]};
    const float amp2 = s_par[D_];

    const int t  = threadIdx.x;
    const int jb = blockIdx.x * 1024;
    const int i0 = blockIdx.y * TI;

    // Lane-contiguous ownership: thread t owns x2 rows jb+t+{0,256,512,768}
    // (32 B lane stride -> coalesced). float4 halves ARE the dim-pairs.
    floatx2 w[4][4];
#pragma unroll
    for (int k = 0; k < 4; ++k) {
        const float* r2 = x2 + (size_t)(jb + t + k * 256) * D_;
        const float4 a = *reinterpret_cast<const float4*>(r2);
        const float4 b = *reinterpret_cast<const float4*>(r2 + 4);
        w[k][0] = floatx2{a.x, a.y};
        w[k][1] = floatx2{a.z, a.w};
        w[k][2] = floatx2{b.x, b.y};
        w[k][3] = floatx2{b.z, b.w};
    }

#pragma unroll
    for (int ii = 0; ii < TI; ++ii) {
        const int i = i0 + ii;
        // Uniform address -> scalar-load path, L1/L2-hot.
        const float4 xa = *reinterpret_cast<const float4*>(x + (size_t)i * D_);
        const float4 xb = *reinterpret_cast<const float4*>(x + (size_t)i * D_ + 4);
        const floatx2 xp0 = floatx2{xa.x, xa.y};
        const floatx2 xp1 = floatx2{xa.z, xa.w};
        const floatx2 xp2 = floatx2{xb.x, xb.y};
        const floatx2 xp3 = floatx2{xb.z, xb.w};

        float r[4];
#pragma unroll
        for (int k = 0; k < 4; ++k) {
            floatx2 d0 = xp0 - w[k][0];
            floatx2 acc2 = d0 * d0 * cp[0];
            floatx2 d1 = xp1 - w[k][1];
            acc2 = __builtin_elementwise_fma(d1 * d1, cp[1], acc2);
            floatx2 d2 = xp2 - w[k][2];
            acc2 = __builtin_elementwise_fma(d2 * d2, cp[2], acc2);
            floatx2 d3 = xp3 - w[k][3];
            acc2 = __builtin_elementwise_fma(d3 * d3, cp[3], acc2);
            float s = acc2.x + acc2.y;      // even+odd partial sums
            r[k] = amp2 * __builtin_amdgcn_exp2f(-s);
        }
        // 4 dword stores off one address register (imm offsets {0,1,2,3}KB).
        float* o = out + (size_t)i * M_ + jb + t;
        o[0]   = r[0];
        o[256] = r[1];
        o[512] = r[2];
        o[768] = r[3];
    }
}

extern "C" void kernel_launch(void* const* d_in, const int* in_sizes, int n_in,
                              void* d_out, int out_size, void* d_ws, size_t ws_size,
                              hipStream_t stream) {
    const float* x    = (const float*)d_in[0];
    const float* x2   = (const float*)d_in[1];
    const float* ramp = (const float*)d_in[2];
    const float* rls  = (const float*)d_in[3];
    float* out = (float*)d_out;

    dim3 block(256);
    dim3 grid(M_ / 1024, N_ / TI);   // (4, 512) = 2048 blocks

    // Slope measurement: REPS identical launches (same work every call,
    // stream-serialized, last write wins). Kernel time = bench delta / (REPS-1).
    for (int rep = 0; rep < REPS; ++rep) {
        rbf_kernel<<<grid, block, 0, stream>>>(x, x2, ramp, rls, out);
    }
}

// Round 17
// 84.190 us; speedup vs baseline: 1.7555x; 1.7555x over previous
//
#include <hip/hip_runtime.h>
#include <math.h>

#define N_ 4096
#define M_ 4096
#define D_ 8
#define TI 8                        // x-rows per block
#define TINY_F 1.17549435e-38f
#define LOG2E_F 1.44269504088896f

typedef float floatx2 __attribute__((ext_vector_type(2)));  // -> v_pk_*_f32

// Numerically stable softplus: log(1+exp(v)) = max(v,0) + log1p(exp(-|v|))
__device__ __forceinline__ float softplus_stable(float v) {
    return fmaxf(v, 0.0f) + log1pf(expf(-fabsf(v)));
}

__global__ __launch_bounds__(256) void rbf_kernel(
    const float* __restrict__ x,      // (N, D)
    const float* __restrict__ x2,     // (M, D)
    const float* __restrict__ ramp,   // (1,)
    const float* __restrict__ rls,    // (D,)
    float* __restrict__ out)          // (N, M)
{
    // [0..7] = (0.5/ls^2)*log2(e), [8] = la = log2(amp^2)  (amp folded into exponent)
    __shared__ float s_par[D_ + 1];
    if (threadIdx.x < D_) {
        float l = softplus_stable(rls[threadIdx.x]) + TINY_F;
        s_par[threadIdx.x] = (0.5f * LOG2E_F) / (l * l);
    } else if (threadIdx.x == D_) {
        float a = softplus_stable(ramp[0]) + TINY_F;
        s_par[D_] = 2.0f * log2f(a);
    }
    __syncthreads();

    floatx2 cp[4];
    cp[0] = floatx2{s_par[0], s_par[1]};
    cp[1] = floatx2{s_par[2], s_par[3]};
    cp[2] = floatx2{s_par[4], s_par[5]};
    cp[3] = floatx2{s_par[6], s_par[7]};
    const float la = s_par[D_];

    const int t  = threadIdx.x;
    const int jb = blockIdx.x * 1024;
    const int i0 = blockIdx.y * TI;

    // Lane-contiguous ownership: thread t owns x2 rows jb+t+{0,256,512,768}
    // (32 B lane stride -> coalesced). float4 halves ARE the dim-pairs.
    floatx2 w[4][4];
    float W2[4];                     // per-column Σ c_d w_d^2 (once per block)
#pragma unroll
    for (int k = 0; k < 4; ++k) {
        const float* r2 = x2 + (size_t)(jb + t + k * 256) * D_;
        const float4 a = *reinterpret_cast<const float4*>(r2);
        const float4 b = *reinterpret_cast<const float4*>(r2 + 4);
        w[k][0] = floatx2{a.x, a.y};
        w[k][1] = floatx2{a.z, a.w};
        w[k][2] = floatx2{b.x, b.y};
        w[k][3] = floatx2{b.z, b.w};
        floatx2 q = cp[0] * w[k][0] * w[k][0];
        q = __builtin_elementwise_fma(cp[1] * w[k][1], w[k][1], q);
        q = __builtin_elementwise_fma(cp[2] * w[k][2], w[k][2], q);
        q = __builtin_elementwise_fma(cp[3] * w[k][3], w[k][3], q);
        W2[k] = q.x + q.y;
    }

#pragma unroll
    for (int ii = 0; ii < TI; ++ii) {
        const int i = i0 + ii;
        const float4 xa = *reinterpret_cast<const float4*>(x + (size_t)i * D_);
        const float4 xb = *reinterpret_cast<const float4*>(x + (size_t)i * D_ + 4);
        const floatx2 xp0 = floatx2{xa.x, xa.y};
        const floatx2 xp1 = floatx2{xa.z, xa.w};
        const floatx2 xp2 = floatx2{xb.x, xb.y};
        const floatx2 xp3 = floatx2{xb.z, xb.w};

        // u = c (.) x ; X2 = Σ c x^2 = Σ u x
        const floatx2 u0 = cp[0] * xp0;
        const floatx2 u1 = cp[1] * xp1;
        const floatx2 u2 = cp[2] * xp2;
        const floatx2 u3 = cp[3] * xp3;
        floatx2 xq = u0 * xp0;
        xq = __builtin_elementwise_fma(u1, xp1, xq);
        xq = __builtin_elementwise_fma(u2, xp2, xq);
        xq = __builtin_elementwise_fma(u3, xp3, xq);
        const float bb = (xq.x + xq.y) - la;   // X2 - la

        float r[4];
#pragma unroll
        for (int k = 0; k < 4; ++k) {
            // out = exp2(la - X2 - W2 + 2*dot) = exp2(fma(2, dot, -(bb + W2[k])))
            floatx2 dp = u0 * w[k][0];
            dp = __builtin_elementwise_fma(u1, w[k][1], dp);
            dp = __builtin_elementwise_fma(u2, w[k][2], dp);
            dp = __builtin_elementwise_fma(u3, w[k][3], dp);
            const float dot  = dp.x + dp.y;
            const float base = bb + W2[k];
            r[k] = __builtin_amdgcn_exp2f(fmaf(2.0f, dot, -base));
        }
        // 4 dword stores off one address register (imm offsets {0,1,2,3}KB).
        float* o = out + (size_t)i * M_ + jb + t;
        o[0]   = r[0];
        o[256] = r[1];
        o[512] = r[2];
        o[768] = r[3];
    }
}

extern "C" void kernel_launch(void* const* d_in, const int* in_sizes, int n_in,
                              void* d_out, int out_size, void* d_ws, size_t ws_size,
                              hipStream_t stream) {
    const float* x    = (const float*)d_in[0];
    const float* x2   = (const float*)d_in[1];
    const float* ramp = (const float*)d_in[2];
    const float* rls  = (const float*)d_in[3];
    float* out = (float*)d_out;

    dim3 block(256);
    dim3 grid(M_ / 1024, N_ / TI);   // (4, 512) = 2048 blocks
    rbf_kernel<<<grid, block, 0, stream>>>(x, x2, ramp, rls, out);
}